// Round 9
// baseline (582.922 us; speedup 1.0000x reference)
//
#include <hip/hip_runtime.h>
#include <hip/hip_bf16.h>
#include <math.h>

#define BATCH 2
#define NTOK 1024
#define DMODEL 512
#define NHEAD 8
#define DH 64
#define NLAYER 4
#define MMODES 256
#define DFFN 2048

typedef unsigned short u16;
typedef __attribute__((ext_vector_type(4))) float f4;
typedef __attribute__((ext_vector_type(8))) short b8;

__device__ __forceinline__ float bf2f(u16 u) { return __uint_as_float(((unsigned)u) << 16); }
__device__ __forceinline__ u16 f2b(float x) {
    unsigned u = __float_as_uint(x);
    return (u16)((u + 0x7FFF + ((u >> 16) & 1)) >> 16);
}
__device__ __forceinline__ float ldx(const void* p, size_t i, int f32) {
    return f32 ? ((const float*)p)[i] : bf2f(((const u16*)p)[i]);
}
__device__ __forceinline__ void async_ld16(const u16* g, u16* l) {
    __builtin_amdgcn_global_load_lds((const __attribute__((address_space(1))) void*)g,
                                     (__attribute__((address_space(3))) void*)l, 16, 0, 0);
}

// ---- block-local dtype probe (768 even u16 of a Gaussian weight buffer) ----
__device__ __forceinline__ int detect_local(const void* probe) {
    const u16* u = (const u16*)probe;
    int big = 0, zer = 0;
    for (int t = threadIdx.x; t < 768; t += 256) {
        u16 w = u[2 * t];
        int e = (w >> 7) & 0xFF;
        if (e >= 137) big++;
        if (w == 0) zer++;
    }
    __shared__ int sb, sz;
    if (threadIdx.x == 0) { sb = 0; sz = 0; }
    __syncthreads();
    atomicAdd(&sb, big);
    atomicAdd(&sz, zer);
    __syncthreads();
    return (sb >= 64 || sz >= 700) ? 1 : 0;
}

// ================= param pack layout (fp32) =================
#define OB_BE 0
#define OB_BQKV 512
#define OB_BO 6656
#define OB_B1 8704
#define OB_B2 16896
#define OB_TEMP 18944
#define OB_L1G 18976
#define OB_L1B 21024
#define OB_L2G 23072
#define OB_L2B 25120
#define OB_FNG 27168
#define OB_FNB 27680
#define OB_MODES 28192
#define OB_TOTAL 28960

// ================= prep: cvt + pack + zero-stats + flag store, one dispatch =================
// grid: [0,4096) cvt | [4096,4210) pack | [4210,4354) zero stats
__global__ __launch_bounds__(256) void prep_kernel(
    const void* phi, const void* coords,
    const void* be_, const void* bq_, const void* bk_, const void* bv_,
    const void* bo_, const void* b1_, const void* b2_, const void* temp_,
    const void* l1g_, const void* l1b_, const void* l2g_, const void* l2b_,
    const void* fng_, const void* fnb_, const void* modes_,
    const void* probe,
    float* __restrict__ xf, float* __restrict__ cf, float* __restrict__ prm,
    float* __restrict__ sbuf, int* __restrict__ flag) {
    int f = detect_local(probe);
    int z = blockIdx.x, tid = threadIdx.x;
    if (z == 0 && tid == 0) flag[0] = f;
    if (z < 4096) {
        int i = z * 256 + tid;
        if (i < BATCH * NTOK * DMODEL) xf[i] = ldx(phi, i, f);
        if (i < BATCH * NTOK * 3) cf[i] = ldx(coords, i, f);
    } else if (z < 4210) {
        int idx = (z - 4096) * 256 + tid;
        if (idx < OB_TOTAL) {
            float v;
            int i = idx;
            if (i < 512) v = ldx(be_, i, f);
            else if ((i -= 512) < 6144) {
                int l = i / 1536, r = i - l * 1536;
                v = (r < 512) ? ldx(bq_, (size_t)l * 512 + r, f)
                  : (r < 1024) ? ldx(bk_, (size_t)l * 512 + r - 512, f)
                  : ldx(bv_, (size_t)l * 512 + r - 1024, f);
            }
            else if ((i -= 6144) < 2048) v = ldx(bo_, i, f);
            else if ((i -= 2048) < 8192) v = ldx(b1_, i, f);
            else if ((i -= 8192) < 2048) v = ldx(b2_, i, f);
            else if ((i -= 2048) < 32)   v = ldx(temp_, i, f);
            else if ((i -= 32) < 2048)   v = ldx(l1g_, i, f);
            else if ((i -= 2048) < 2048) v = ldx(l1b_, i, f);
            else if ((i -= 2048) < 2048) v = ldx(l2g_, i, f);
            else if ((i -= 2048) < 2048) v = ldx(l2b_, i, f);
            else if ((i -= 2048) < 512)  v = ldx(fng_, i, f);
            else if ((i -= 512) < 512)   v = ldx(fnb_, i, f);
            else { i -= 512; v = ldx(modes_, i, f); }
            prm[idx] = v;
        }
    } else {
        int idx = (z - 4210) * 256 + tid;   // 144 blocks * 256 = 36864 = 9*2048*2
        sbuf[idx] = 0.f;
    }
}

// ================= weight transpose: one kernel, all matrices =================
__device__ __forceinline__ void tr_tile(const void* src, size_t sbase, u16* dst,
                                        size_t dbase, int R, int C, int dstRowOff,
                                        int c0, int r0, int f) {
    __shared__ float t[32][33];
    int tx = threadIdx.x & 31, ty8 = threadIdx.x >> 5;
#pragma unroll
    for (int rr = 0; rr < 4; rr++) {
        int r = r0 + ty8 + rr * 8;
        t[ty8 + rr * 8][tx] = ldx(src, sbase + (size_t)r * C + c0 + tx, f);
    }
    __syncthreads();
#pragma unroll
    for (int rr = 0; rr < 4; rr++) {
        int c = c0 + ty8 + rr * 8;
        dst[dbase + (size_t)(dstRowOff + c) * R + r0 + tx] = f2b(t[tx][ty8 + rr * 8]);
    }
}
__global__ __launch_bounds__(256) void tr_all(const void* wq_, const void* wk_, const void* wv_,
                                              const void* wo_, const void* We_,
                                              const void* w1_, const void* w2_,
                                              u16* wqkvT, u16* woT, u16* WeT,
                                              u16* w1T, u16* w2T,
                                              const int* __restrict__ fl) {
    int f = fl[0];
    int z = blockIdx.x;
    if (z < 3072) {
        int mat = z >> 8, t = z & 255;
        int l = mat / 3, m3 = mat - l * 3;
        const void* s = (m3 == 0) ? wq_ : (m3 == 1) ? wk_ : wv_;
        tr_tile(s, (size_t)l * 512 * 512, wqkvT, (size_t)l * 1536 * 512,
                512, 512, m3 * 512, (t & 15) * 32, (t >> 4) * 32, f);
    } else if (z < 4096) {
        int zz = z - 3072, l = zz >> 8, t = zz & 255;
        tr_tile(wo_, (size_t)l * 512 * 512, woT, (size_t)l * 512 * 512,
                512, 512, 0, (t & 15) * 32, (t >> 4) * 32, f);
    } else if (z < 4352) {
        int t = z - 4096;
        tr_tile(We_, 0, WeT, 0, 512, 512, 0, (t & 15) * 32, (t >> 4) * 32, f);
    } else if (z < 8448) {
        int zz = z - 4352, l = zz >> 10, t = zz & 1023;
        tr_tile(w1_, (size_t)l * 512 * 2048, w1T, (size_t)l * 2048 * 512,
                512, 2048, 0, (t & 63) * 32, (t >> 6) * 32, f);
    } else {
        int zz = z - 8448, l = zz >> 10, t = zz & 1023;
        tr_tile(w2_, (size_t)l * 2048 * 512, w2T, (size_t)l * 512 * 2048,
                2048, 512, 0, (t & 15) * 32, (t >> 4) * 32, f);
    }
}

// ================= Fourier features + distance stats (merged) =================
__global__ __launch_bounds__(256) void feats_dstat(const float* __restrict__ cf,
                                                   const float* __restrict__ modesF,
                                                   u16* __restrict__ ff,
                                                   float* __restrict__ part,
                                                   u16* __restrict__ dist) {
    int row = blockIdx.x;
    {
        int m = threadIdx.x;
        float cx = cf[row * 3 + 0], cy = cf[row * 3 + 1], cz = cf[row * 3 + 2];
        float ph = cx * modesF[m * 3 + 0] + cy * modesF[m * 3 + 1] + cz * modesF[m * 3 + 2];
        ff[(size_t)row * 512 + m] = f2b(cosf(ph));
        ff[(size_t)row * 512 + MMODES + m] = f2b(sinf(ph));
    }
    int b = row >> 10, i = row & 1023;
    const float* cb = cf + (size_t)b * NTOK * 3;
    float xi = cb[i * 3], yi = cb[i * 3 + 1], zi = cb[i * 3 + 2];
    float ls = 0.f, ls2 = 0.f;
    for (int j = threadIdx.x; j < NTOK; j += 256) {
        float dx = xi - (cb[j * 3] + 1e-5f);
        float dy = yi - (cb[j * 3 + 1] + 1e-5f);
        float dz = zi - (cb[j * 3 + 2] + 1e-5f);
        float d = sqrtf(dx * dx + dy * dy + dz * dz);
        if (dist) dist[(((size_t)row) << 10) + j] = f2b(d);
        ls += d; ls2 += d * d;
    }
    for (int off = 32; off; off >>= 1) {
        ls += __shfl_down(ls, off);
        ls2 += __shfl_down(ls2, off);
    }
    __shared__ float rs[4], rs2[4];
    int wid = threadIdx.x >> 6;
    if ((threadIdx.x & 63) == 0) { rs[wid] = ls; rs2[wid] = ls2; }
    __syncthreads();
    if (threadIdx.x == 0) {
        part[row] = rs[0] + rs[1] + rs[2] + rs[3];
        part[2048 + row] = rs2[0] + rs2[1] + rs2[2] + rs2[3];
    }
}
__global__ __launch_bounds__(256) void dreduce_kernel(const float* __restrict__ part,
                                                      float* __restrict__ inv_std) {
    int b = blockIdx.x;
    double s = 0.0, s2 = 0.0;
    for (int t = threadIdx.x; t < NTOK; t += 256) {
        s += (double)part[b * NTOK + t];
        s2 += (double)part[2048 + b * NTOK + t];
    }
    for (int off = 32; off; off >>= 1) {
        s += __shfl_down(s, off);
        s2 += __shfl_down(s2, off);
    }
    __shared__ double ds[4], ds2[4];
    int wid = threadIdx.x >> 6;
    if ((threadIdx.x & 63) == 0) { ds[wid] = s; ds2[wid] = s2; }
    __syncthreads();
    if (threadIdx.x == 0) {
        double S = ds[0] + ds[1] + ds[2] + ds[3];
        double S2 = ds2[0] + ds2[1] + ds2[2] + ds2[3];
        double n = (double)NTOK * (double)NTOK;
        double mean = S / n;
        double var = (S2 - n * mean * mean) / (n - 1.0);
        inv_std[b] = (float)(1.0 / sqrt(var));
    }
}

// ================= final LayerNorm (apply-only, stats precomputed) =================
__global__ __launch_bounds__(256) void ln_out_kernel(const float* __restrict__ x,
                                                     const float* __restrict__ sIn,
                                                     const float* __restrict__ gp,
                                                     const float* __restrict__ bp,
                                                     void* __restrict__ out,
                                                     const int* __restrict__ fl) {
    int f = fl[0];
    int row = blockIdx.x, tid = threadIdx.x;
    const float* xr = x + (size_t)row * DMODEL;
    float mean = sIn[row * 2] * (1.0f / DMODEL);
    float var = sIn[row * 2 + 1] * (1.0f / DMODEL) - mean * mean;
    float r = rsqrtf(var + 1e-5f);
    float v0 = xr[tid], v1 = xr[tid + 256];
    float o0 = (v0 - mean) * r * gp[tid] + bp[tid];
    float o1 = (v1 - mean) * r * gp[tid + 256] + bp[tid + 256];
    size_t i0 = (size_t)row * DMODEL + tid;
    if (f) { ((float*)out)[i0] = o0; ((float*)out)[i0 + 256] = o1; }
    else   { ((u16*)out)[i0] = f2b(o0); ((u16*)out)[i0 + 256] = f2b(o1); }
}

// ================= MFMA GEMM: BK=64, async B staging =================
// LNA: A is fp32 xf; normalize with sIn row stats + g/b during staging (VGPR path).
// STATS: epilogue accumulates per-row sum/sumsq of output into sOut (atomics).
// QKV: output cols >=1024 go to VT[b][h][d][j].
template <int FM, int FN, int ACT, int RES, int OUTBF, int QKV, int LNA, int STATS>
__global__ __launch_bounds__(256) void gemm_mfma(const void* __restrict__ A,
                                                 const u16* __restrict__ BT,
                                                 const float* __restrict__ bias,
                                                 const float* __restrict__ res,
                                                 void* __restrict__ Cp,
                                                 u16* __restrict__ VTp,
                                                 const float* __restrict__ sIn,
                                                 const float* __restrict__ gIn,
                                                 const float* __restrict__ bIn,
                                                 float* __restrict__ sOut,
                                                 int M, int N, int K) {
    constexpr int BM = 32 * FM, BN = 32 * FN;
    constexpr int PA = BM / 64, PB = BN / 64;
    __shared__ u16 As[2 * BM * 32];
    __shared__ u16 Bs[2 * BN * 32];
    const int m0 = blockIdx.y * BM, n0 = blockIdx.x * BN;
    const int tid = threadIdx.x, lane = tid & 63, wid = tid >> 6;
    const int wm = (wid >> 1) * (16 * FM), wn = (wid & 1) * (16 * FN);
    const int quad = lane >> 4, low = lane & 15;
    const int srow = tid >> 2, scol = (tid & 3) * 8;
    // LNA: hoist per-row stats (row fixed per thread per pass)
    float meanp[PA], rstdp[PA];
    const float* Af = (const float*)A;
    if (LNA) {
#pragma unroll
        for (int p = 0; p < PA; p++) {
            int row = m0 + p * 64 + srow;
            float sm = sIn[row * 2] * (1.0f / DMODEL);
            float sq = sIn[row * 2 + 1] * (1.0f / DMODEL);
            meanp[p] = sm;
            rstdp[p] = rsqrtf(sq - sm * sm + 1e-5f);
        }
    }
    f4 acc[FM][FN] = {};
    for (int k0 = 0; k0 < K; k0 += 64) {
#pragma unroll
        for (int ks = 0; ks < 2; ks++) {
            int kk = k0 + ks * 32 + scol;
#pragma unroll
            for (int p = 0; p < PA; p++) {
                if (LNA) {
                    const float* xr = Af + (size_t)(m0 + p * 64 + srow) * K + kk;
                    float4 x0 = *(const float4*)xr;
                    float4 x1 = *(const float4*)(xr + 4);
                    float4 g0 = *(const float4*)(gIn + kk);
                    float4 g1 = *(const float4*)(gIn + kk + 4);
                    float4 b0 = *(const float4*)(bIn + kk);
                    float4 b1 = *(const float4*)(bIn + kk + 4);
                    float mn = meanp[p], rs = rstdp[p];
                    u16 tmp[8];
                    tmp[0] = f2b((x0.x - mn) * rs * g0.x + b0.x);
                    tmp[1] = f2b((x0.y - mn) * rs * g0.y + b0.y);
                    tmp[2] = f2b((x0.z - mn) * rs * g0.z + b0.z);
                    tmp[3] = f2b((x0.w - mn) * rs * g0.w + b0.w);
                    tmp[4] = f2b((x1.x - mn) * rs * g1.x + b1.x);
                    tmp[5] = f2b((x1.y - mn) * rs * g1.y + b1.y);
                    tmp[6] = f2b((x1.z - mn) * rs * g1.z + b1.z);
                    tmp[7] = f2b((x1.w - mn) * rs * g1.w + b1.w);
                    *(uint4*)(As + ks * BM * 32 + p * 2048 + tid * 8) = *(uint4*)tmp;
                } else {
                    async_ld16((const u16*)A + (size_t)(m0 + p * 64 + srow) * K + kk,
                               As + ks * BM * 32 + p * 2048 + wid * 512);
                }
            }
#pragma unroll
            for (int p = 0; p < PB; p++)
                async_ld16(BT + (size_t)(n0 + p * 64 + srow) * K + kk,
                           Bs + ks * BN * 32 + p * 2048 + wid * 512);
        }
        __syncthreads();
#pragma unroll
        for (int ks = 0; ks < 2; ks++) {
            b8 af[FM], bfr[FN];
#pragma unroll
            for (int i = 0; i < FM; i++)
                af[i] = *(const b8*)(As + ks * BM * 32 + (wm + i * 16 + low) * 32 + quad * 8);
#pragma unroll
            for (int j = 0; j < FN; j++)
                bfr[j] = *(const b8*)(Bs + ks * BN * 32 + (wn + j * 16 + low) * 32 + quad * 8);
#pragma unroll
            for (int i = 0; i < FM; i++)
#pragma unroll
                for (int j = 0; j < FN; j++)
                    acc[i][j] = __builtin_amdgcn_mfma_f32_16x16x32_bf16(af[i], bfr[j], acc[i][j], 0, 0, 0);
        }
        __syncthreads();
    }
    float rsum[FM][4], rsq[FM][4];
    if (STATS) {
#pragma unroll
        for (int i = 0; i < FM; i++)
#pragma unroll
            for (int r = 0; r < 4; r++) { rsum[i][r] = 0.f; rsq[i][r] = 0.f; }
    }
#pragma unroll
    for (int i = 0; i < FM; i++) {
#pragma unroll
        for (int j = 0; j < FN; j++) {
            int gn = n0 + wn + j * 16 + low;
            float bv = bias[gn];
            if (QKV && gn >= 1024) {
                int h = (gn - 1024) >> 6, d = (gn - 1024) & 63;
                int gmb = m0 + wm + i * 16 + quad * 4;
                int bb = gmb >> 10, jj = gmb & 1023;
                ushort4 pk;
                pk.x = f2b(acc[i][j][0] + bv);
                pk.y = f2b(acc[i][j][1] + bv);
                pk.z = f2b(acc[i][j][2] + bv);
                pk.w = f2b(acc[i][j][3] + bv);
                *(ushort4*)(VTp + ((size_t)(bb * 8 + h) * 64 + d) * 1024 + jj) = pk;
            } else {
#pragma unroll
                for (int r = 0; r < 4; r++) {
                    int gm = m0 + wm + i * 16 + quad * 4 + r;
                    float v = acc[i][j][r] + bv;
                    if (ACT) v = 0.5f * v * (1.0f + erff(v * 0.70710678f));
                    if (RES) v += res[(size_t)gm * N + gn];
                    if (OUTBF) ((u16*)Cp)[(size_t)gm * N + gn] = f2b(v);
                    else       ((float*)Cp)[(size_t)gm * N + gn] = v;
                    if (STATS) { rsum[i][r] += v; rsq[i][r] += v * v; }
                }
            }
        }
    }
    if (STATS) {
#pragma unroll
        for (int i = 0; i < FM; i++)
#pragma unroll
            for (int r = 0; r < 4; r++) {
                float a = rsum[i][r], q = rsq[i][r];
                a += __shfl_xor(a, 1); q += __shfl_xor(q, 1);
                a += __shfl_xor(a, 2); q += __shfl_xor(q, 2);
                a += __shfl_xor(a, 4); q += __shfl_xor(q, 4);
                a += __shfl_xor(a, 8); q += __shfl_xor(q, 8);
                if (low == 0) {
                    int row = m0 + wm + i * 16 + quad * 4 + r;
                    atomicAdd(&sOut[row * 2], a);
                    atomicAdd(&sOut[row * 2 + 1], q);
                }
            }
    }
}

// ================= MFMA flash attention (V from pre-transposed VT) =================
template <int USE_DIST>
__global__ __launch_bounds__(256) void attn_mfma(const u16* __restrict__ qkv,
                                                 const u16* __restrict__ VT,
                                                 const float* __restrict__ cf,
                                                 const float* __restrict__ inv_std,
                                                 const float* __restrict__ tempF, int l,
                                                 const u16* __restrict__ dist,
                                                 u16* __restrict__ o) {
    const int it = blockIdx.x, h = blockIdx.y, b = blockIdx.z;
    const int i0 = it * 32, tid = threadIdx.x;
    const int lane = tid & 63, wid = tid >> 6;
    const int g = wid >> 1, p = wid & 1;
    const int quad = lane >> 4, low = lane & 15;
    __shared__ u16 Ks[2][64][72];
    __shared__ u16 Vs[2][64][72];
    __shared__ u16 Ps[4][16][72];
    __shared__ float s_ci[32][3];
    __shared__ float s_cj[2][64][3];
    const size_t rbase = (size_t)b * NTOK;
    const u16* VTh = VT + ((size_t)(b * 8 + h)) * 65536;
    b8 qf0, qf1;
    {
        const u16* qp = qkv + (rbase + i0 + g * 16 + low) * 1536 + h * 64;
        qf0 = *(const b8*)(qp + quad * 8);
        qf1 = *(const b8*)(qp + 32 + quad * 8);
    }
    if (!USE_DIST && tid < 32) {
        s_ci[tid][0] = cf[(rbase + i0 + tid) * 3 + 0];
        s_ci[tid][1] = cf[(rbase + i0 + tid) * 3 + 1];
        s_ci[tid][2] = cf[(rbase + i0 + tid) * 3 + 2];
    }
    float t0 = tempF[l * 8 + h];
    float spw = (fmaxf(t0, 0.f) + log1pf(__expf(-fabsf(t0)))) * inv_std[b];
    float mold[4] = {-1e30f, -1e30f, -1e30f, -1e30f};
    float lsum[4] = {0.f, 0.f, 0.f, 0.f};
    f4 oacc[4] = {};
    __syncthreads();
    float cqx[4], cqy[4], cqz[4];
    const u16* drow[4];
#pragma unroll
    for (int r = 0; r < 4; r++) {
        int ii = g * 16 + quad * 4 + r;
        if (USE_DIST) drow[r] = dist + ((rbase + i0 + ii) << 10);
        else { cqx[r] = s_ci[ii][0]; cqy[r] = s_ci[ii][1]; cqz[r] = s_ci[ii][2]; }
    }
    for (int t = 0; t < 8; t++) {
        __syncthreads();
#pragma unroll
        for (int tt = 0; tt < 2; tt++) {
            int j0s = (t * 2 + tt) * 64;
            int j = tid >> 2, dc = (tid & 3) * 16;
            const u16* kp = qkv + (rbase + j0s + j) * 1536 + 512 + h * 64 + dc;
            *(uint4*)&Ks[tt][j][dc] = *(const uint4*)kp;
            *(uint4*)&Ks[tt][j][dc + 8] = *(const uint4*)(kp + 8);
            const u16* vp = VTh + (size_t)j * 1024 + j0s + dc;
            *(uint4*)&Vs[tt][j][dc] = *(const uint4*)vp;
            *(uint4*)&Vs[tt][j][dc + 8] = *(const uint4*)(vp + 8);
            if (!USE_DIST && tid < 64) {
                s_cj[tt][tid][0] = cf[(rbase + j0s + tid) * 3 + 0] + 1e-5f;
                s_cj[tt][tid][1] = cf[(rbase + j0s + tid) * 3 + 1] + 1e-5f;
                s_cj[tt][tid][2] = cf[(rbase + j0s + tid) * 3 + 2] + 1e-5f;
            }
        }
        __syncthreads();
        const int j0 = (t * 2 + p) * 64;
        f4 sacc[4] = {};
#pragma unroll
        for (int jb = 0; jb < 4; jb++) {
            b8 bk0 = *(const b8*)&Ks[p][jb * 16 + low][quad * 8];
            b8 bk1 = *(const b8*)&Ks[p][jb * 16 + low][32 + quad * 8];
            sacc[jb] = __builtin_amdgcn_mfma_f32_16x16x32_bf16(qf0, bk0, sacc[jb], 0, 0, 0);
            sacc[jb] = __builtin_amdgcn_mfma_f32_16x16x32_bf16(qf1, bk1, sacc[jb], 0, 0, 0);
        }
        float sv[4][4];
#pragma unroll
        for (int jb = 0; jb < 4; jb++) {
            int j = jb * 16 + low;
            if (USE_DIST) {
#pragma unroll
                for (int r = 0; r < 4; r++)
                    sv[jb][r] = sacc[jb][r] * 0.125f - spw * bf2f(drow[r][j0 + j]);
            } else {
                float cjx = s_cj[p][j][0], cjy = s_cj[p][j][1], cjz = s_cj[p][j][2];
#pragma unroll
                for (int r = 0; r < 4; r++) {
                    float dx = cqx[r] - cjx, dy = cqy[r] - cjy, dz = cqz[r] - cjz;
                    sv[jb][r] = sacc[jb][r] * 0.125f - spw * sqrtf(dx * dx + dy * dy + dz * dz);
                }
            }
        }
        float alpha[4];
#pragma unroll
        for (int r = 0; r < 4; r++) {
            float mx = fmaxf(fmaxf(sv[0][r], sv[1][r]), fmaxf(sv[2][r], sv[3][r]));
            mx = fmaxf(mx, __shfl_xor(mx, 1));
            mx = fmaxf(mx, __shfl_xor(mx, 2));
            mx = fmaxf(mx, __shfl_xor(mx, 4));
            mx = fmaxf(mx, __shfl_xor(mx, 8));
            float mn = fmaxf(mold[r], mx);
            alpha[r] = __expf(mold[r] - mn);
            mold[r] = mn;
            float ps = 0.f;
#pragma unroll
            for (int jb = 0; jb < 4; jb++) {
                float pp = __expf(sv[jb][r] - mn);
                Ps[wid][quad * 4 + r][jb * 16 + low] = f2b(pp);
                ps += pp;
            }
            ps += __shfl_xor(ps, 1);
            ps += __shfl_xor(ps, 2);
            ps += __shfl_xor(ps, 4);
            ps += __shfl_xor(ps, 8);
            lsum[r] = lsum[r] * alpha[r] + ps;
        }
#pragma unroll
        for (int db = 0; db < 4; db++)
#pragma unroll
            for (int r = 0; r < 4; r++) oacc[db][r] *= alpha[r];
        b8 ap0 = *(const b8*)&Ps[wid][low][quad * 8];
        b8 ap1 = *(const b8*)&Ps[wid][low][32 + quad * 8];
#pragma unroll
        for (int db = 0; db < 4; db++) {
            b8 bv0 = *(const b8*)&Vs[p][db * 16 + low][quad * 8];
            b8 bv1 = *(const b8*)&Vs[p][db * 16 + low][32 + quad * 8];
            oacc[db] = __builtin_amdgcn_mfma_f32_16x16x32_bf16(ap0, bv0, oacc[db], 0, 0, 0);
            oacc[db] = __builtin_amdgcn_mfma_f32_16x16x32_bf16(ap1, bv1, oacc[db], 0, 0, 0);
        }
    }
    __syncthreads();
    float* scr = (float*)&Ks[0][0][0];
    float* Og = scr + g * 1088;
    float* Ml = Og + 1024;
    if (p == 1) {
#pragma unroll
        for (int db = 0; db < 4; db++)
#pragma unroll
            for (int r = 0; r < 4; r++)
                Og[(quad * 4 + r) * 64 + db * 16 + low] = oacc[db][r];
        if (low == 0) {
#pragma unroll
            for (int r = 0; r < 4; r++) {
                Ml[quad * 4 + r] = mold[r];
                Ml[16 + quad * 4 + r] = lsum[r];
            }
        }
    }
    __syncthreads();
    if (p == 0) {
#pragma unroll
        for (int r = 0; r < 4; r++) {
            int row = quad * 4 + r;
            float m1 = Ml[row], l1 = Ml[16 + row];
            float mm = fmaxf(mold[r], m1);
            float a0 = __expf(mold[r] - mm), a1 = __expf(m1 - mm);
            float rl = 1.f / (lsum[r] * a0 + l1 * a1);
            u16* op = o + (rbase + i0 + g * 16 + row) * 512 + h * 64 + low;
#pragma unroll
            for (int db = 0; db < 4; db++) {
                float v = oacc[db][r] * a0 + Og[row * 64 + db * 16 + low] * a1;
                op[db * 16] = f2b(v * rl);
            }
        }
    }
}

extern "C" void kernel_launch(void* const* d_in, const int* in_sizes, int n_in,
                              void* d_out, int out_size, void* d_ws, size_t ws_size,
                              hipStream_t stream) {
    const void* phi    = d_in[0];
    const void* coords = d_in[1];
    const void* modes  = d_in[2];
    const void* We     = d_in[3];
    const void* be     = d_in[4];
    const void* wq     = d_in[5];
    const void* bq     = d_in[6];
    const void* wk     = d_in[7];
    const void* bk     = d_in[8];
    const void* wv     = d_in[9];
    const void* bv     = d_in[10];
    const void* wo     = d_in[11];
    const void* bo     = d_in[12];
    const void* temp   = d_in[13];
    const void* ln1g   = d_in[14];
    const void* ln1b   = d_in[15];
    const void* ln2g   = d_in[16];
    const void* ln2b   = d_in[17];
    const void* w1     = d_in[18];
    const void* b1     = d_in[19];
    const void* w2     = d_in[20];
    const void* b2     = d_in[21];
    const void* fng    = d_in[22];
    const void* fnb    = d_in[23];

    const int R = BATCH * NTOK;  // 2048
    char* ws = (char*)d_ws;
    const size_t MB = 1u << 20;
    float* xf   = (float*)(ws);                 // [2048][512] fp32   4 MB
    u16*  of    = (u16*)(ws + 6 * MB);          // [2048][512] bf16   2 MB
    u16*  pool  = (u16*)(ws + 8 * MB);          // ff | qkv+VT | hf
    u16*  ff    = pool;
    u16*  qkvb  = pool;                         // [2048][1536] (q,k valid)
    u16*  VTb   = (u16*)(ws + 14 * MB);         // [2][8][64][1024] 2 MB
    u16*  hf    = pool;                         // [2048][2048] (FFN)
    u16*  WeT   = (u16*)(ws + 16 * MB);
    u16*  wqkvT = (u16*)(ws + 16 * MB + 512 * 1024);
    u16*  woT   = (u16*)(ws + 22 * MB + 512 * 1024);
    u16*  w1T   = (u16*)(ws + 24 * MB + 512 * 1024);
    u16*  w2T   = (u16*)(ws + 32 * MB + 512 * 1024);
    float* prm  = (float*)(ws + 40 * MB + 512 * 1024);
    float* cf   = (float*)(ws + 41 * MB);
    float* part = (float*)(ws + 41 * MB + 128 * 1024);
    float* inv_std = (float*)(ws + 41 * MB + 192 * 1024);
    int*   flag = (int*)(ws + 41 * MB + 192 * 1024 + 64);
    float* sbuf = (float*)(ws + 41 * MB + 256 * 1024);  // 9 x [2048][2] = 147 KB
    u16* dist = (ws_size >= (size_t)46 * MB) ? (u16*)(ws + 42 * MB) : nullptr;
    // stats buffer u: S(u) = sbuf + u*4096. u=0: post-encode; 1+2l: post-wo; 2+2l: post-w2.

    prep_kernel<<<4354, 256, 0, stream>>>(phi, coords, be, bq, bk, bv, bo, b1, b2, temp,
                                          ln1g, ln1b, ln2g, ln2b, fng, fnb, modes, wq,
                                          xf, cf, prm, sbuf, flag);
    tr_all<<<12544, 256, 0, stream>>>(wq, wk, wv, wo, We, w1, w2,
                                      wqkvT, woT, WeT, w1T, w2T, flag);
    feats_dstat<<<R, 256, 0, stream>>>(cf, prm + OB_MODES, ff, part, dist);
    dreduce_kernel<<<BATCH, 256, 0, stream>>>(part, inv_std);
    // encode: xf = phi + ff @ We + be, stats -> S0
    gemm_mfma<2, 2, 0, 1, 0, 0, 0, 1><<<dim3(8, 32), 256, 0, stream>>>(
        ff, WeT, prm + OB_BE, xf, xf, nullptr, nullptr, nullptr, nullptr, sbuf,
        R, DMODEL, DMODEL);

    for (int l = 0; l < NLAYER; l++) {
        float* Sin1 = sbuf + (size_t)(2 * l) * 4096;       // pre-ln1 stats
        float* Sow  = sbuf + (size_t)(2 * l + 1) * 4096;   // post-wo stats
        float* Sow2 = sbuf + (size_t)(2 * l + 2) * 4096;   // post-w2 stats
        // qkv: A = LN1(xf) fused; V part -> VT
        gemm_mfma<2, 2, 0, 0, 1, 1, 1, 0><<<dim3(24, 32), 256, 0, stream>>>(
            xf, wqkvT + (size_t)l * 1536 * 512, prm + OB_BQKV + l * 1536, nullptr, qkvb, VTb,
            Sin1, prm + OB_L1G + l * 512, prm + OB_L1B + l * 512, nullptr,
            R, 1536, DMODEL);
        if (dist)
            attn_mfma<1><<<dim3(32, NHEAD, BATCH), 256, 0, stream>>>(
                qkvb, VTb, cf, inv_std, prm + OB_TEMP, l, dist, of);
        else
            attn_mfma<0><<<dim3(32, NHEAD, BATCH), 256, 0, stream>>>(
                qkvb, VTb, cf, inv_std, prm + OB_TEMP, l, nullptr, of);
        // wo: xf += of @ woT + bo, stats -> Sow
        gemm_mfma<2, 2, 0, 1, 0, 0, 0, 1><<<dim3(8, 32), 256, 0, stream>>>(
            of, woT + (size_t)l * 512 * 512, prm + OB_BO + l * 512, xf, xf, nullptr,
            nullptr, nullptr, nullptr, Sow, R, DMODEL, DMODEL);
        // w1: A = LN2(xf) fused, GELU -> hf
        gemm_mfma<4, 2, 1, 0, 1, 0, 1, 0><<<dim3(32, 16), 256, 0, stream>>>(
            xf, w1T + (size_t)l * 2048 * 512, prm + OB_B1 + l * 2048, nullptr, hf, nullptr,
            Sow, prm + OB_L2G + l * 512, prm + OB_L2B + l * 512, nullptr,
            R, DFFN, DMODEL);
        // w2: xf += hf @ w2T + b2, stats -> Sow2
        gemm_mfma<2, 2, 0, 1, 0, 0, 0, 1><<<dim3(8, 32), 256, 0, stream>>>(
            hf, w2T + (size_t)l * 512 * 2048, prm + OB_B2 + l * 512, xf, xf, nullptr,
            nullptr, nullptr, nullptr, Sow2, R, DMODEL, DFFN);
    }
    ln_out_kernel<<<R, 256, 0, stream>>>(xf, sbuf + (size_t)(2 * NLAYER) * 4096,
                                         prm + OB_FNG, prm + OB_FNB, d_out, flag);
}

// Round 10
// 536.244 us; speedup vs baseline: 1.0870x; 1.0870x over previous
//
#include <hip/hip_runtime.h>
#include <hip/hip_bf16.h>
#include <math.h>

#define BATCH 2
#define NTOK 1024
#define DMODEL 512
#define NHEAD 8
#define DH 64
#define NLAYER 4
#define MMODES 256
#define DFFN 2048

typedef unsigned short u16;
typedef __attribute__((ext_vector_type(4))) float f4;
typedef __attribute__((ext_vector_type(8))) short b8;

__device__ __forceinline__ float bf2f(u16 u) { return __uint_as_float(((unsigned)u) << 16); }
__device__ __forceinline__ u16 f2b(float x) {
    unsigned u = __float_as_uint(x);
    return (u16)((u + 0x7FFF + ((u >> 16) & 1)) >> 16);
}
__device__ __forceinline__ float ldx(const void* p, size_t i, int f32) {
    return f32 ? ((const float*)p)[i] : bf2f(((const u16*)p)[i]);
}
__device__ __forceinline__ void async_ld16(const u16* g, u16* l) {
    __builtin_amdgcn_global_load_lds((const __attribute__((address_space(1))) void*)g,
                                     (__attribute__((address_space(3))) void*)l, 16, 0, 0);
}

// ---- block-local dtype probe ----
__device__ __forceinline__ int detect_local(const void* probe) {
    const u16* u = (const u16*)probe;
    int big = 0, zer = 0;
    for (int t = threadIdx.x; t < 768; t += 256) {
        u16 w = u[2 * t];
        int e = (w >> 7) & 0xFF;
        if (e >= 137) big++;
        if (w == 0) zer++;
    }
    __shared__ int sb, sz;
    if (threadIdx.x == 0) { sb = 0; sz = 0; }
    __syncthreads();
    atomicAdd(&sb, big);
    atomicAdd(&sz, zer);
    __syncthreads();
    return (sb >= 64 || sz >= 700) ? 1 : 0;
}

// ================= param pack layout (fp32) =================
#define OB_BE 0
#define OB_BQKV 512
#define OB_BO 6656
#define OB_B1 8704
#define OB_B2 16896
#define OB_TEMP 18944
#define OB_L1G 18976
#define OB_L1B 21024
#define OB_L2G 23072
#define OB_L2B 25120
#define OB_FNG 27168
#define OB_FNB 27680
#define OB_MODES 28192
#define OB_TOTAL 28960

// ================= prep: cvt + pack + flag, one dispatch =================
__global__ __launch_bounds__(256) void prep_kernel(
    const void* phi, const void* coords,
    const void* be_, const void* bq_, const void* bk_, const void* bv_,
    const void* bo_, const void* b1_, const void* b2_, const void* temp_,
    const void* l1g_, const void* l1b_, const void* l2g_, const void* l2b_,
    const void* fng_, const void* fnb_, const void* modes_,
    const void* probe,
    float* __restrict__ xf, float* __restrict__ cf, float* __restrict__ prm,
    int* __restrict__ flag) {
    int f = detect_local(probe);
    int z = blockIdx.x, tid = threadIdx.x;
    if (z == 0 && tid == 0) flag[0] = f;
    if (z < 4096) {
        int i = z * 256 + tid;
        if (i < BATCH * NTOK * DMODEL) xf[i] = ldx(phi, i, f);
        if (i < BATCH * NTOK * 3) cf[i] = ldx(coords, i, f);
    } else {
        int idx = (z - 4096) * 256 + tid;
        if (idx < OB_TOTAL) {
            float v;
            int i = idx;
            if (i < 512) v = ldx(be_, i, f);
            else if ((i -= 512) < 6144) {
                int l = i / 1536, r = i - l * 1536;
                v = (r < 512) ? ldx(bq_, (size_t)l * 512 + r, f)
                  : (r < 1024) ? ldx(bk_, (size_t)l * 512 + r - 512, f)
                  : ldx(bv_, (size_t)l * 512 + r - 1024, f);
            }
            else if ((i -= 6144) < 2048) v = ldx(bo_, i, f);
            else if ((i -= 2048) < 8192) v = ldx(b1_, i, f);
            else if ((i -= 8192) < 2048) v = ldx(b2_, i, f);
            else if ((i -= 2048) < 32)   v = ldx(temp_, i, f);
            else if ((i -= 32) < 2048)   v = ldx(l1g_, i, f);
            else if ((i -= 2048) < 2048) v = ldx(l1b_, i, f);
            else if ((i -= 2048) < 2048) v = ldx(l2g_, i, f);
            else if ((i -= 2048) < 2048) v = ldx(l2b_, i, f);
            else if ((i -= 2048) < 512)  v = ldx(fng_, i, f);
            else if ((i -= 512) < 512)   v = ldx(fnb_, i, f);
            else { i -= 512; v = ldx(modes_, i, f); }
            prm[idx] = v;
        }
    }
}

// ================= weight transpose: one kernel, all matrices =================
__device__ __forceinline__ void tr_tile(const void* src, size_t sbase, u16* dst,
                                        size_t dbase, int R, int C, int dstRowOff,
                                        int c0, int r0, int f) {
    __shared__ float t[32][33];
    int tx = threadIdx.x & 31, ty8 = threadIdx.x >> 5;
#pragma unroll
    for (int rr = 0; rr < 4; rr++) {
        int r = r0 + ty8 + rr * 8;
        t[ty8 + rr * 8][tx] = ldx(src, sbase + (size_t)r * C + c0 + tx, f);
    }
    __syncthreads();
#pragma unroll
    for (int rr = 0; rr < 4; rr++) {
        int c = c0 + ty8 + rr * 8;
        dst[dbase + (size_t)(dstRowOff + c) * R + r0 + tx] = f2b(t[tx][ty8 + rr * 8]);
    }
}
__global__ __launch_bounds__(256) void tr_all(const void* wq_, const void* wk_, const void* wv_,
                                              const void* wo_, const void* We_,
                                              const void* w1_, const void* w2_,
                                              u16* wqkvT, u16* woT, u16* WeT,
                                              u16* w1T, u16* w2T,
                                              const int* __restrict__ fl) {
    int f = fl[0];
    int z = blockIdx.x;
    if (z < 3072) {
        int mat = z >> 8, t = z & 255;
        int l = mat / 3, m3 = mat - l * 3;
        const void* s = (m3 == 0) ? wq_ : (m3 == 1) ? wk_ : wv_;
        tr_tile(s, (size_t)l * 512 * 512, wqkvT, (size_t)l * 1536 * 512,
                512, 512, m3 * 512, (t & 15) * 32, (t >> 4) * 32, f);
    } else if (z < 4096) {
        int zz = z - 3072, l = zz >> 8, t = zz & 255;
        tr_tile(wo_, (size_t)l * 512 * 512, woT, (size_t)l * 512 * 512,
                512, 512, 0, (t & 15) * 32, (t >> 4) * 32, f);
    } else if (z < 4352) {
        int t = z - 4096;
        tr_tile(We_, 0, WeT, 0, 512, 512, 0, (t & 15) * 32, (t >> 4) * 32, f);
    } else if (z < 8448) {
        int zz = z - 4352, l = zz >> 10, t = zz & 1023;
        tr_tile(w1_, (size_t)l * 512 * 2048, w1T, (size_t)l * 2048 * 512,
                512, 2048, 0, (t & 63) * 32, (t >> 6) * 32, f);
    } else {
        int zz = z - 8448, l = zz >> 10, t = zz & 1023;
        tr_tile(w2_, (size_t)l * 2048 * 512, w2T, (size_t)l * 512 * 2048,
                2048, 512, 0, (t & 15) * 32, (t >> 4) * 32, f);
    }
}

// ================= Fourier features + distance stats (merged) =================
__global__ __launch_bounds__(256) void feats_dstat(const float* __restrict__ cf,
                                                   const float* __restrict__ modesF,
                                                   u16* __restrict__ ff,
                                                   float* __restrict__ part,
                                                   u16* __restrict__ dist) {
    int row = blockIdx.x;
    {
        int m = threadIdx.x;
        float cx = cf[row * 3 + 0], cy = cf[row * 3 + 1], cz = cf[row * 3 + 2];
        float ph = cx * modesF[m * 3 + 0] + cy * modesF[m * 3 + 1] + cz * modesF[m * 3 + 2];
        ff[(size_t)row * 512 + m] = f2b(cosf(ph));
        ff[(size_t)row * 512 + MMODES + m] = f2b(sinf(ph));
    }
    int b = row >> 10, i = row & 1023;
    const float* cb = cf + (size_t)b * NTOK * 3;
    float xi = cb[i * 3], yi = cb[i * 3 + 1], zi = cb[i * 3 + 2];
    float ls = 0.f, ls2 = 0.f;
    for (int j = threadIdx.x; j < NTOK; j += 256) {
        float dx = xi - (cb[j * 3] + 1e-5f);
        float dy = yi - (cb[j * 3 + 1] + 1e-5f);
        float dz = zi - (cb[j * 3 + 2] + 1e-5f);
        float d = sqrtf(dx * dx + dy * dy + dz * dz);
        if (dist) dist[(((size_t)row) << 10) + j] = f2b(d);
        ls += d; ls2 += d * d;
    }
    for (int off = 32; off; off >>= 1) {
        ls += __shfl_down(ls, off);
        ls2 += __shfl_down(ls2, off);
    }
    __shared__ float rs[4], rs2[4];
    int wid = threadIdx.x >> 6;
    if ((threadIdx.x & 63) == 0) { rs[wid] = ls; rs2[wid] = ls2; }
    __syncthreads();
    if (threadIdx.x == 0) {
        part[row] = rs[0] + rs[1] + rs[2] + rs[3];
        part[2048 + row] = rs2[0] + rs2[1] + rs2[2] + rs2[3];
    }
}
__global__ __launch_bounds__(256) void dreduce_kernel(const float* __restrict__ part,
                                                      float* __restrict__ inv_std) {
    int b = blockIdx.x;
    double s = 0.0, s2 = 0.0;
    for (int t = threadIdx.x; t < NTOK; t += 256) {
        s += (double)part[b * NTOK + t];
        s2 += (double)part[2048 + b * NTOK + t];
    }
    for (int off = 32; off; off >>= 1) {
        s += __shfl_down(s, off);
        s2 += __shfl_down(s2, off);
    }
    __shared__ double ds[4], ds2[4];
    int wid = threadIdx.x >> 6;
    if ((threadIdx.x & 63) == 0) { ds[wid] = s; ds2[wid] = s2; }
    __syncthreads();
    if (threadIdx.x == 0) {
        double S = ds[0] + ds[1] + ds[2] + ds[3];
        double S2 = ds2[0] + ds2[1] + ds2[2] + ds2[3];
        double n = (double)NTOK * (double)NTOK;
        double mean = S / n;
        double var = (S2 - n * mean * mean) / (n - 1.0);
        inv_std[b] = (float)(1.0 / sqrt(var));
    }
}

// ================= LayerNorm: fp32 in -> bf16 out (standalone — fast & proven) =================
__global__ __launch_bounds__(256) void ln_bf_kernel(const float* __restrict__ x,
                                                    const float* __restrict__ gp,
                                                    const float* __restrict__ bp,
                                                    u16* __restrict__ y) {
    int row = blockIdx.x, tid = threadIdx.x;
    const float* xr = x + (size_t)row * DMODEL;
    float v0 = xr[tid], v1 = xr[tid + 256];
    float s = v0 + v1, s2 = v0 * v0 + v1 * v1;
    for (int off = 32; off; off >>= 1) {
        s += __shfl_down(s, off);
        s2 += __shfl_down(s2, off);
    }
    __shared__ float ls[4], ls2[4];
    int wid = tid >> 6;
    if ((tid & 63) == 0) { ls[wid] = s; ls2[wid] = s2; }
    __syncthreads();
    s = ls[0] + ls[1] + ls[2] + ls[3];
    s2 = ls2[0] + ls2[1] + ls2[2] + ls2[3];
    float mean = s * (1.0f / DMODEL);
    float var = s2 * (1.0f / DMODEL) - mean * mean;
    float r = rsqrtf(var + 1e-5f);
    y[(size_t)row * DMODEL + tid] = f2b((v0 - mean) * r * gp[tid] + bp[tid]);
    y[(size_t)row * DMODEL + tid + 256] = f2b((v1 - mean) * r * gp[tid + 256] + bp[tid + 256]);
}
__global__ __launch_bounds__(256) void ln_out_kernel(const float* __restrict__ x,
                                                     const float* __restrict__ gp,
                                                     const float* __restrict__ bp,
                                                     void* __restrict__ out,
                                                     const int* __restrict__ fl) {
    int f = fl[0];
    int row = blockIdx.x, tid = threadIdx.x;
    const float* xr = x + (size_t)row * DMODEL;
    float v0 = xr[tid], v1 = xr[tid + 256];
    float s = v0 + v1, s2 = v0 * v0 + v1 * v1;
    for (int off = 32; off; off >>= 1) {
        s += __shfl_down(s, off);
        s2 += __shfl_down(s2, off);
    }
    __shared__ float ls[4], ls2[4];
    int wid = tid >> 6;
    if ((tid & 63) == 0) { ls[wid] = s; ls2[wid] = s2; }
    __syncthreads();
    s = ls[0] + ls[1] + ls[2] + ls[3];
    s2 = ls2[0] + ls2[1] + ls2[2] + ls2[3];
    float mean = s * (1.0f / DMODEL);
    float var = s2 * (1.0f / DMODEL) - mean * mean;
    float r = rsqrtf(var + 1e-5f);
    float o0 = (v0 - mean) * r * gp[tid] + bp[tid];
    float o1 = (v1 - mean) * r * gp[tid + 256] + bp[tid + 256];
    size_t i0 = (size_t)row * DMODEL + tid;
    if (f) { ((float*)out)[i0] = o0; ((float*)out)[i0 + 256] = o1; }
    else   { ((u16*)out)[i0] = f2b(o0); ((u16*)out)[i0 + 256] = f2b(o1); }
}

// ================= MFMA GEMM: BK=64, async staging; QKV V->VT; ATOM split-K =================
// ATOM: grid.z = SPLITK slices of K; each block atomicAdds its partial into fp32 C
// (C pre-holds the residual). Bias added by the z==0 slice only.
template <int FM, int FN, int ACT, int RES, int OUTBF, int QKV, int ATOM, int SPLITK>
__global__ __launch_bounds__(256) void gemm_mfma(const u16* __restrict__ A,
                                                 const u16* __restrict__ BT,
                                                 const float* __restrict__ bias,
                                                 const float* __restrict__ res,
                                                 void* __restrict__ Cp,
                                                 u16* __restrict__ VTp,
                                                 int M, int N, int K) {
    constexpr int BM = 32 * FM, BN = 32 * FN;
    constexpr int PA = BM / 64, PB = BN / 64;
    __shared__ u16 As[2 * BM * 32];
    __shared__ u16 Bs[2 * BN * 32];
    const int m0 = blockIdx.y * BM, n0 = blockIdx.x * BN;
    const int kslice = (SPLITK > 1) ? (K / SPLITK) : K;
    const int kbeg = (SPLITK > 1) ? blockIdx.z * kslice : 0;
    const int tid = threadIdx.x, lane = tid & 63, wid = tid >> 6;
    const int wm = (wid >> 1) * (16 * FM), wn = (wid & 1) * (16 * FN);
    const int quad = lane >> 4, low = lane & 15;
    const int srow = tid >> 2, scol = (tid & 3) * 8;
    f4 acc[FM][FN] = {};
    for (int k0 = kbeg; k0 < kbeg + kslice; k0 += 64) {
#pragma unroll
        for (int ks = 0; ks < 2; ks++) {
            int kk = k0 + ks * 32 + scol;
#pragma unroll
            for (int p = 0; p < PA; p++)
                async_ld16(A + (size_t)(m0 + p * 64 + srow) * K + kk,
                           As + ks * BM * 32 + p * 2048 + wid * 512);
#pragma unroll
            for (int p = 0; p < PB; p++)
                async_ld16(BT + (size_t)(n0 + p * 64 + srow) * K + kk,
                           Bs + ks * BN * 32 + p * 2048 + wid * 512);
        }
        __syncthreads();
#pragma unroll
        for (int ks = 0; ks < 2; ks++) {
            b8 af[FM], bfr[FN];
#pragma unroll
            for (int i = 0; i < FM; i++)
                af[i] = *(const b8*)(As + ks * BM * 32 + (wm + i * 16 + low) * 32 + quad * 8);
#pragma unroll
            for (int j = 0; j < FN; j++)
                bfr[j] = *(const b8*)(Bs + ks * BN * 32 + (wn + j * 16 + low) * 32 + quad * 8);
#pragma unroll
            for (int i = 0; i < FM; i++)
#pragma unroll
                for (int j = 0; j < FN; j++)
                    acc[i][j] = __builtin_amdgcn_mfma_f32_16x16x32_bf16(af[i], bfr[j], acc[i][j], 0, 0, 0);
        }
        __syncthreads();
    }
#pragma unroll
    for (int i = 0; i < FM; i++) {
#pragma unroll
        for (int j = 0; j < FN; j++) {
            int gn = n0 + wn + j * 16 + low;
            float bv = bias[gn];
            if (QKV && gn >= 1024) {
                int h = (gn - 1024) >> 6, d = (gn - 1024) & 63;
                int gmb = m0 + wm + i * 16 + quad * 4;
                int bb = gmb >> 10, jj = gmb & 1023;
                ushort4 pk;
                pk.x = f2b(acc[i][j][0] + bv);
                pk.y = f2b(acc[i][j][1] + bv);
                pk.z = f2b(acc[i][j][2] + bv);
                pk.w = f2b(acc[i][j][3] + bv);
                *(ushort4*)(VTp + ((size_t)(bb * 8 + h) * 64 + d) * 1024 + jj) = pk;
            } else if (ATOM) {
#pragma unroll
                for (int r = 0; r < 4; r++) {
                    int gm = m0 + wm + i * 16 + quad * 4 + r;
                    float v = acc[i][j][r];
                    if (blockIdx.z == 0) v += bv;
                    atomicAdd(&((float*)Cp)[(size_t)gm * N + gn], v);
                }
            } else {
#pragma unroll
                for (int r = 0; r < 4; r++) {
                    int gm = m0 + wm + i * 16 + quad * 4 + r;
                    float v = acc[i][j][r] + bv;
                    if (ACT) v = 0.5f * v * (1.0f + erff(v * 0.70710678f));
                    if (RES) v += res[(size_t)gm * N + gn];
                    if (OUTBF) ((u16*)Cp)[(size_t)gm * N + gn] = f2b(v);
                    else       ((float*)Cp)[(size_t)gm * N + gn] = v;
                }
            }
        }
    }
}

// ================= MFMA flash attention (unchanged, verified) =================
template <int USE_DIST>
__global__ __launch_bounds__(256) void attn_mfma(const u16* __restrict__ qkv,
                                                 const u16* __restrict__ VT,
                                                 const float* __restrict__ cf,
                                                 const float* __restrict__ inv_std,
                                                 const float* __restrict__ tempF, int l,
                                                 const u16* __restrict__ dist,
                                                 u16* __restrict__ o) {
    const int it = blockIdx.x, h = blockIdx.y, b = blockIdx.z;
    const int i0 = it * 32, tid = threadIdx.x;
    const int lane = tid & 63, wid = tid >> 6;
    const int g = wid >> 1, p = wid & 1;
    const int quad = lane >> 4, low = lane & 15;
    __shared__ u16 Ks[2][64][72];
    __shared__ u16 Vs[2][64][72];
    __shared__ u16 Ps[4][16][72];
    __shared__ float s_ci[32][3];
    __shared__ float s_cj[2][64][3];
    const size_t rbase = (size_t)b * NTOK;
    const u16* VTh = VT + ((size_t)(b * 8 + h)) * 65536;
    b8 qf0, qf1;
    {
        const u16* qp = qkv + (rbase + i0 + g * 16 + low) * 1536 + h * 64;
        qf0 = *(const b8*)(qp + quad * 8);
        qf1 = *(const b8*)(qp + 32 + quad * 8);
    }
    if (!USE_DIST && tid < 32) {
        s_ci[tid][0] = cf[(rbase + i0 + tid) * 3 + 0];
        s_ci[tid][1] = cf[(rbase + i0 + tid) * 3 + 1];
        s_ci[tid][2] = cf[(rbase + i0 + tid) * 3 + 2];
    }
    float t0 = tempF[l * 8 + h];
    float spw = (fmaxf(t0, 0.f) + log1pf(__expf(-fabsf(t0)))) * inv_std[b];
    float mold[4] = {-1e30f, -1e30f, -1e30f, -1e30f};
    float lsum[4] = {0.f, 0.f, 0.f, 0.f};
    f4 oacc[4] = {};
    __syncthreads();
    float cqx[4], cqy[4], cqz[4];
    const u16* drow[4];
#pragma unroll
    for (int r = 0; r < 4; r++) {
        int ii = g * 16 + quad * 4 + r;
        if (USE_DIST) drow[r] = dist + ((rbase + i0 + ii) << 10);
        else { cqx[r] = s_ci[ii][0]; cqy[r] = s_ci[ii][1]; cqz[r] = s_ci[ii][2]; }
    }
    for (int t = 0; t < 8; t++) {
        __syncthreads();
#pragma unroll
        for (int tt = 0; tt < 2; tt++) {
            int j0s = (t * 2 + tt) * 64;
            int j = tid >> 2, dc = (tid & 3) * 16;
            const u16* kp = qkv + (rbase + j0s + j) * 1536 + 512 + h * 64 + dc;
            *(uint4*)&Ks[tt][j][dc] = *(const uint4*)kp;
            *(uint4*)&Ks[tt][j][dc + 8] = *(const uint4*)(kp + 8);
            const u16* vp = VTh + (size_t)j * 1024 + j0s + dc;
            *(uint4*)&Vs[tt][j][dc] = *(const uint4*)vp;
            *(uint4*)&Vs[tt][j][dc + 8] = *(const uint4*)(vp + 8);
            if (!USE_DIST && tid < 64) {
                s_cj[tt][tid][0] = cf[(rbase + j0s + tid) * 3 + 0] + 1e-5f;
                s_cj[tt][tid][1] = cf[(rbase + j0s + tid) * 3 + 1] + 1e-5f;
                s_cj[tt][tid][2] = cf[(rbase + j0s + tid) * 3 + 2] + 1e-5f;
            }
        }
        __syncthreads();
        const int j0 = (t * 2 + p) * 64;
        f4 sacc[4] = {};
#pragma unroll
        for (int jb = 0; jb < 4; jb++) {
            b8 bk0 = *(const b8*)&Ks[p][jb * 16 + low][quad * 8];
            b8 bk1 = *(const b8*)&Ks[p][jb * 16 + low][32 + quad * 8];
            sacc[jb] = __builtin_amdgcn_mfma_f32_16x16x32_bf16(qf0, bk0, sacc[jb], 0, 0, 0);
            sacc[jb] = __builtin_amdgcn_mfma_f32_16x16x32_bf16(qf1, bk1, sacc[jb], 0, 0, 0);
        }
        float sv[4][4];
#pragma unroll
        for (int jb = 0; jb < 4; jb++) {
            int j = jb * 16 + low;
            if (USE_DIST) {
#pragma unroll
                for (int r = 0; r < 4; r++)
                    sv[jb][r] = sacc[jb][r] * 0.125f - spw * bf2f(drow[r][j0 + j]);
            } else {
                float cjx = s_cj[p][j][0], cjy = s_cj[p][j][1], cjz = s_cj[p][j][2];
#pragma unroll
                for (int r = 0; r < 4; r++) {
                    float dx = cqx[r] - cjx, dy = cqy[r] - cjy, dz = cqz[r] - cjz;
                    sv[jb][r] = sacc[jb][r] * 0.125f - spw * sqrtf(dx * dx + dy * dy + dz * dz);
                }
            }
        }
        float alpha[4];
#pragma unroll
        for (int r = 0; r < 4; r++) {
            float mx = fmaxf(fmaxf(sv[0][r], sv[1][r]), fmaxf(sv[2][r], sv[3][r]));
            mx = fmaxf(mx, __shfl_xor(mx, 1));
            mx = fmaxf(mx, __shfl_xor(mx, 2));
            mx = fmaxf(mx, __shfl_xor(mx, 4));
            mx = fmaxf(mx, __shfl_xor(mx, 8));
            float mn = fmaxf(mold[r], mx);
            alpha[r] = __expf(mold[r] - mn);
            mold[r] = mn;
            float ps = 0.f;
#pragma unroll
            for (int jb = 0; jb < 4; jb++) {
                float pp = __expf(sv[jb][r] - mn);
                Ps[wid][quad * 4 + r][jb * 16 + low] = f2b(pp);
                ps += pp;
            }
            ps += __shfl_xor(ps, 1);
            ps += __shfl_xor(ps, 2);
            ps += __shfl_xor(ps, 4);
            ps += __shfl_xor(ps, 8);
            lsum[r] = lsum[r] * alpha[r] + ps;
        }
#pragma unroll
        for (int db = 0; db < 4; db++)
#pragma unroll
            for (int r = 0; r < 4; r++) oacc[db][r] *= alpha[r];
        b8 ap0 = *(const b8*)&Ps[wid][low][quad * 8];
        b8 ap1 = *(const b8*)&Ps[wid][low][32 + quad * 8];
#pragma unroll
        for (int db = 0; db < 4; db++) {
            b8 bv0 = *(const b8*)&Vs[p][db * 16 + low][quad * 8];
            b8 bv1 = *(const b8*)&Vs[p][db * 16 + low][32 + quad * 8];
            oacc[db] = __builtin_amdgcn_mfma_f32_16x16x32_bf16(ap0, bv0, oacc[db], 0, 0, 0);
            oacc[db] = __builtin_amdgcn_mfma_f32_16x16x32_bf16(ap1, bv1, oacc[db], 0, 0, 0);
        }
    }
    __syncthreads();
    float* scr = (float*)&Ks[0][0][0];
    float* Og = scr + g * 1088;
    float* Ml = Og + 1024;
    if (p == 1) {
#pragma unroll
        for (int db = 0; db < 4; db++)
#pragma unroll
            for (int r = 0; r < 4; r++)
                Og[(quad * 4 + r) * 64 + db * 16 + low] = oacc[db][r];
        if (low == 0) {
#pragma unroll
            for (int r = 0; r < 4; r++) {
                Ml[quad * 4 + r] = mold[r];
                Ml[16 + quad * 4 + r] = lsum[r];
            }
        }
    }
    __syncthreads();
    if (p == 0) {
#pragma unroll
        for (int r = 0; r < 4; r++) {
            int row = quad * 4 + r;
            float m1 = Ml[row], l1 = Ml[16 + row];
            float mm = fmaxf(mold[r], m1);
            float a0 = __expf(mold[r] - mm), a1 = __expf(m1 - mm);
            float rl = 1.f / (lsum[r] * a0 + l1 * a1);
            u16* op = o + (rbase + i0 + g * 16 + row) * 512 + h * 64 + low;
#pragma unroll
            for (int db = 0; db < 4; db++) {
                float v = oacc[db][r] * a0 + Og[row * 64 + db * 16 + low] * a1;
                op[db * 16] = f2b(v * rl);
            }
        }
    }
}

extern "C" void kernel_launch(void* const* d_in, const int* in_sizes, int n_in,
                              void* d_out, int out_size, void* d_ws, size_t ws_size,
                              hipStream_t stream) {
    const void* phi    = d_in[0];
    const void* coords = d_in[1];
    const void* modes  = d_in[2];
    const void* We     = d_in[3];
    const void* be     = d_in[4];
    const void* wq     = d_in[5];
    const void* bq     = d_in[6];
    const void* wk     = d_in[7];
    const void* bk     = d_in[8];
    const void* wv     = d_in[9];
    const void* bv     = d_in[10];
    const void* wo     = d_in[11];
    const void* bo     = d_in[12];
    const void* temp   = d_in[13];
    const void* ln1g   = d_in[14];
    const void* ln1b   = d_in[15];
    const void* ln2g   = d_in[16];
    const void* ln2b   = d_in[17];
    const void* w1     = d_in[18];
    const void* b1     = d_in[19];
    const void* w2     = d_in[20];
    const void* b2     = d_in[21];
    const void* fng    = d_in[22];
    const void* fnb    = d_in[23];

    const int R = BATCH * NTOK;  // 2048
    char* ws = (char*)d_ws;
    const size_t MB = 1u << 20;
    float* xf   = (float*)(ws);                 // [2048][512] fp32   4 MB
    u16*  yf    = (u16*)(ws + 4 * MB);          // [2048][512] bf16   2 MB
    u16*  of    = (u16*)(ws + 6 * MB);          // [2048][512] bf16   2 MB
    u16*  pool  = (u16*)(ws + 8 * MB);          // ff | qkv+VT | hf
    u16*  ff    = pool;
    u16*  qkvb  = pool;                         // [2048][1536] (q,k valid)
    u16*  VTb   = (u16*)(ws + 14 * MB);         // [2][8][64][1024] 2 MB
    u16*  hf    = pool;                         // [2048][2048] (FFN)
    u16*  WeT   = (u16*)(ws + 16 * MB);
    u16*  wqkvT = (u16*)(ws + 16 * MB + 512 * 1024);
    u16*  woT   = (u16*)(ws + 22 * MB + 512 * 1024);
    u16*  w1T   = (u16*)(ws + 24 * MB + 512 * 1024);
    u16*  w2T   = (u16*)(ws + 32 * MB + 512 * 1024);
    float* prm  = (float*)(ws + 40 * MB + 512 * 1024);
    float* cf   = (float*)(ws + 41 * MB);
    float* part = (float*)(ws + 41 * MB + 128 * 1024);
    float* inv_std = (float*)(ws + 41 * MB + 192 * 1024);
    int*   flag = (int*)(ws + 41 * MB + 192 * 1024 + 64);
    u16* dist = (ws_size >= (size_t)46 * MB) ? (u16*)(ws + 42 * MB) : nullptr;

    prep_kernel<<<4210, 256, 0, stream>>>(phi, coords, be, bq, bk, bv, bo, b1, b2, temp,
                                          ln1g, ln1b, ln2g, ln2b, fng, fnb, modes, wq,
                                          xf, cf, prm, flag);
    tr_all<<<12544, 256, 0, stream>>>(wq, wk, wv, wo, We, w1, w2,
                                      wqkvT, woT, WeT, w1T, w2T, flag);
    feats_dstat<<<R, 256, 0, stream>>>(cf, prm + OB_MODES, ff, part, dist);
    dreduce_kernel<<<BATCH, 256, 0, stream>>>(part, inv_std);
    // encode: xf = phi + ff @ We + be
    gemm_mfma<2, 2, 0, 1, 0, 0, 0, 0><<<dim3(8, 32), 256, 0, stream>>>(
        ff, WeT, prm + OB_BE, xf, xf, nullptr, R, DMODEL, DMODEL);

    for (int l = 0; l < NLAYER; l++) {
        ln_bf_kernel<<<R, 256, 0, stream>>>(xf, prm + OB_L1G + l * 512, prm + OB_L1B + l * 512, yf);
        gemm_mfma<2, 2, 0, 0, 1, 1, 0, 0><<<dim3(24, 32), 256, 0, stream>>>(
            yf, wqkvT + (size_t)l * 1536 * 512, prm + OB_BQKV + l * 1536, nullptr, qkvb, VTb,
            R, 1536, DMODEL);
        if (dist)
            attn_mfma<1><<<dim3(32, NHEAD, BATCH), 256, 0, stream>>>(
                qkvb, VTb, cf, inv_std, prm + OB_TEMP, l, dist, of);
        else
            attn_mfma<0><<<dim3(32, NHEAD, BATCH), 256, 0, stream>>>(
                qkvb, VTb, cf, inv_std, prm + OB_TEMP, l, nullptr, of);
        // wo: xf += of @ woT + bo  (split-K=2, atomic accumulate into xf)
        gemm_mfma<2, 2, 0, 0, 0, 0, 1, 2><<<dim3(8, 32, 2), 256, 0, stream>>>(
            of, woT + (size_t)l * 512 * 512, prm + OB_BO + l * 512, nullptr, xf, nullptr,
            R, DMODEL, DMODEL);
        ln_bf_kernel<<<R, 256, 0, stream>>>(xf, prm + OB_L2G + l * 512, prm + OB_L2B + l * 512, yf);
        gemm_mfma<4, 2, 1, 0, 1, 0, 0, 0><<<dim3(32, 16), 256, 0, stream>>>(
            yf, w1T + (size_t)l * 2048 * 512, prm + OB_B1 + l * 2048, nullptr, hf, nullptr,
            R, DFFN, DMODEL);
        // w2: xf += hf @ w2T + b2  (split-K=4, atomic accumulate into xf)
        gemm_mfma<2, 2, 0, 0, 0, 0, 1, 4><<<dim3(8, 32, 4), 256, 0, stream>>>(
            hf, w2T + (size_t)l * 512 * 2048, prm + OB_B2 + l * 512, nullptr, xf, nullptr,
            R, DMODEL, DFFN);
    }
    ln_out_kernel<<<R, 256, 0, stream>>>(xf, prm + OB_FNG, prm + OB_FNB, d_out, flag);
}